// Round 10
// baseline (336.947 us; speedup 1.0000x reference)
//
#include <hip/hip_runtime.h>
#include <hip/hip_bf16.h>

#define DIV_UP(a,b) (((a)+(b)-1)/(b))

typedef __attribute__((ext_vector_type(8))) short short8;
typedef __attribute__((ext_vector_type(4))) float f32x4;

__device__ __forceinline__ ushort bf16_bits(float x) {
    return __builtin_bit_cast(ushort, __float2bfloat16(x));
}

// async global->LDS 16B DMA: LDS dest is wave-uniform base + lane*16,
// global src is per-lane (pre-swizzled source pattern, guide rule 21)
__device__ __forceinline__ void gload_lds16(const ushort* g, ushort* l) {
    __builtin_amdgcn_global_load_lds(
        (const __attribute__((address_space(1))) void*)g,
        (__attribute__((address_space(3))) void*)l, 16, 0, 0);
}

// ---------------------------------------------------------------------------
// Zero ONLY the pad halos (top row + left col) of act1/act2 and vbuf.
// ---------------------------------------------------------------------------
__global__ __launch_bounds__(256) void halo_zero_kernel(
    uint4* __restrict__ act1, uint4* __restrict__ act2,
    float4* __restrict__ vbuf) {
    const int b = blockIdx.x, tid = threadIdx.x;
    const uint4 z = {0u, 0u, 0u, 0u};
    uint4* a1 = act1 + (size_t)b * 33800;          // 65*65*64 bf16 = 33800 uint4
    for (int i = tid; i < 520; i += 256) a1[i] = z;
    for (int i = tid; i < 512; i += 256) {
        int r = (i >> 3) + 1;
        a1[r * 520 + (i & 7)] = z;
    }
    uint4* a2 = act2 + (size_t)b * 17424;          // 33*33*128 bf16 = 17424 uint4
    for (int i = tid; i < 528; i += 256) a2[i] = z;
    for (int i = tid; i < 512; i += 256) {
        int r = (i >> 4) + 1;
        a2[r * 528 + (i & 15)] = z;
    }
    int idx = b * 256 + tid;
    float4 zf = {0.f, 0.f, 0.f, 0.f};
    if (idx < 16384) vbuf[idx] = zf;
}

// ---------------------------------------------------------------------------
// conv1 weights OIHW [64,3,3,3] -> bf16 [oc][32] (k = c*9+kh*3+kw, pad 27..31)
// ---------------------------------------------------------------------------
__global__ void repack_w1_kernel(const float* __restrict__ src,
                                 __hip_bfloat16* __restrict__ dst) {
    int t = blockIdx.x * blockDim.x + threadIdx.x;
    if (t >= 2048) return;
    int k  = t & 31;
    int oc = t >> 5;
    dst[t] = (k < 27) ? __float2bfloat16(src[oc * 27 + k])
                      : __float2bfloat16(0.f);
}

// ---------------------------------------------------------------------------
// conv weights OIHW [O][C][9] fp32 -> bf16 [tap][C/8][O][8]:
// dst[((tap*SEG + sg)*O + n)*8 + e] = W[n][sg*8+e][tap]  (SEG = C/8)
// ---------------------------------------------------------------------------
__global__ void repack_w_kernel(const float* __restrict__ src,
                                __hip_bfloat16* __restrict__ dst, int O, int C) {
    int t = blockIdx.x * blockDim.x + threadIdx.x;
    if (t >= O * C * 9) return;
    int e   = t & 7;
    int r   = t >> 3;
    int n   = r % O;
    int q   = r / O;
    int SEG = C >> 3;
    int sg  = q % SEG;
    int tap = q / SEG;
    dst[t] = __float2bfloat16(src[(n * C + sg * 8 + e) * 9 + tap]);
}

// ---------------------------------------------------------------------------
// conv1 as MFMA implicit-GEMM (round-4 proven version):
// async-DMA input stage -> reg im2col -> swizzled Al -> MFMA -> direct stores
// ---------------------------------------------------------------------------
__global__ __launch_bounds__(256) void conv1_mfma_kernel(
    const float* __restrict__ in,
    const __hip_bfloat16* __restrict__ wB,   // [64][32] bf16
    const float* __restrict__ bias,
    __hip_bfloat16* __restrict__ out) {
    const int tid  = threadIdx.x;
    const int lane = tid & 63;
    const int wv   = tid >> 6;
    const int l15  = lane & 15;
    const int quad = lane >> 4;
    const int tile = blockIdx.x;             // 0..15, 4 oh rows each
    const int b    = blockIdx.y;
    const int oh0  = tile << 2;

    __shared__ __align__(16) char smem[30208];
    float*  sx = (float*)smem;               // [27][128] fp32, row q = c*9+r
    ushort* Al = (ushort*)(smem + 13824);    // [256][32] bf16 swizzled, 16 KB

    const float* ip  = in + (size_t)b * 3 * 128 * 128;
    const int    ih0 = 2 * oh0 - 1;

    // stage 27 rows x 128 fp32 = 864 16B chunks, linear LDS dest
#pragma unroll
    for (int it = 0; it < 4; ++it) {
        int e = (it << 8) + tid;
        if (e < 864) {
            int q = e >> 5, k = e & 31;      // row q, chunk k
            int c = q / 9, r = q - c * 9;
            int row = ih0 + r;
            if (row < 0) row = 0;            // clamp; masked in im2col
            gload_lds16((const ushort*)(ip + c * 16384 + row * 128 + k * 4),
                        (ushort*)smem + (size_t)e * 8);
        }
    }
    __syncthreads();   // drains vmcnt -> input resident in LDS

    // reg im2col: thread owns px = tid; 27 taps from sx with edge masks
    const int px = tid, ohl = px >> 6, ow = px & 63;
    union { uint4 u4[4]; ushort us[32]; } rowv;
#pragma unroll
    for (int c = 0; c < 3; ++c)
#pragma unroll
        for (int kh = 0; kh < 3; ++kh) {
            const bool rok = (ih0 + 2 * ohl + kh) >= 0;
            const float* srow = sx + (c * 9 + 2 * ohl + kh) * 128;
#pragma unroll
            for (int kw = 0; kw < 3; ++kw) {
                int iw = 2 * ow + kw - 1;
                bool ok = rok && (iw >= 0);
                float x = srow[iw < 0 ? 0 : iw];
                rowv.us[c * 9 + kh * 3 + kw] = bf16_bits(ok ? x : 0.f);
            }
        }
#pragma unroll
    for (int k = 27; k < 32; ++k) rowv.us[k] = 0;
#pragma unroll
    for (int q = 0; q < 4; ++q)
        *(uint4*)(Al + px * 32 + (((q ^ (px >> 1)) & 3) << 3)) = rowv.u4[q];

    // weight fragment (4 KB table, L2-hot): af rows = oc
    short8 af[4], bf[4];
#pragma unroll
    for (int i = 0; i < 4; ++i)
        af[i] = __builtin_bit_cast(short8,
            *(const uint4*)(wB + ((i * 16 + l15) * 32 + quad * 8)));

    __syncthreads();   // Al visible (exchange itself is intra-wave)

#pragma unroll
    for (int j = 0; j < 4; ++j) {
        int p = wv * 64 + j * 16 + l15;
        bf[j] = __builtin_bit_cast(short8,
            *(const uint4*)(Al + p * 32 + (((quad ^ (p >> 1)) & 3) << 3)));
    }
    f32x4 acc[4][4];
#pragma unroll
    for (int i = 0; i < 4; ++i)
#pragma unroll
        for (int j = 0; j < 4; ++j)
            acc[i][j] = __builtin_amdgcn_mfma_f32_16x16x32_bf16(
                af[i], bf[j], (f32x4){0.f, 0.f, 0.f, 0.f}, 0, 0, 0);

    float4 bv[4];
#pragma unroll
    for (int i = 0; i < 4; ++i)
        bv[i] = *(const float4*)(bias + i * 16 + quad * 4);

    // direct stores: D frag (col=px=j*16+l15 wave-local, row=oc=i*16+quad*4+r)
    __hip_bfloat16* ob = out + (((size_t)b * 65 + oh0 + 1) * 65 + 1) * 64;
#pragma unroll
    for (int j = 0; j < 4; ++j) {
        const int oww = j * 16 + l15;
        __hip_bfloat16* op = ob + ((size_t)(wv * 65) + oww) * 64 + quad * 4;
#pragma unroll
        for (int i = 0; i < 4; ++i) {
            union { uint2 u2; ushort us[4]; } pk;
#pragma unroll
            for (int r = 0; r < 4; ++r)
                pk.us[r] = bf16_bits(
                    fmaxf(acc[i][j][r] + ((const float*)&bv[i])[r], 0.f));
            *(uint2*)(op + i * 16) = pk.u2;
        }
    }
}

// ---------------------------------------------------------------------------
// conv2 implicit-GEMM v3: M-tile = 32 px (1 oh x 32 ow), N = 128 oc;
// wave = 32 px x 32 oc (af[2]/bf[2]/acc[2][2]). Stage 3 rows x 65 px x
// 64 ch = 24960 B (full 128B lines, full-3-bit XOR chunk swizzle) ->
// 6 blocks/CU for deep cross-block stage/compute overlap.
// ---------------------------------------------------------------------------
__global__ __launch_bounds__(256, 6) void conv2_gemm_kernel(
    const __hip_bfloat16* __restrict__ act,
    const __hip_bfloat16* __restrict__ wtB,   // [tap][8][128][8]
    const float* __restrict__ bias,
    __hip_bfloat16* __restrict__ out) {
    const int tid  = threadIdx.x;
    const int lane = tid & 63;
    const int w    = tid >> 6;
    const int l15  = lane & 15;
    const int quad = lane >> 4;
    const int per  = gridDim.x >> 3;
    const int Mt   = (blockIdx.x & 7) * per + (blockIdx.x >> 3);
    const int bimg = Mt >> 5;
    const int oh0  = Mt & 31;                // 1 output row per tile

    __shared__ __align__(16) char smem[24960];   // 195 px * 128 B
    ushort* As = (ushort*)smem;
    ushort* Cs = (ushort*)smem;                  // epilogue alias (8.4 KB)

    f32x4 acc[2][2];
#pragma unroll
    for (int i = 0; i < 2; ++i)
#pragma unroll
        for (int j = 0; j < 2; ++j) acc[i][j] = (f32x4){0.f, 0.f, 0.f, 0.f};

    const int wn = w << 5;                   // wave owns 32 oc
    const size_t abase = ((size_t)(bimg * 65 + 2 * oh0)) * 65 * 64;
    const ushort* ap = (const ushort*)act;

    // stage 3 rows x 65 px x 64 ch = 1560 16B chunks, full lines.
    // dest chunk t of pixel p holds source chunk t^((p>>1)&7) (ch = 8*q)
#pragma unroll
    for (int it = 0; it < 7; ++it) {
        int c = (it << 8) + tid;
        if (c < 1560) {
            int p = c >> 3, t = c & 7;       // p = r*65 + px
            int q = t ^ ((p >> 1) & 7);
            gload_lds16(ap + abase + (size_t)p * 64 + q * 8,
                        As + (size_t)c * 8);
        }
    }
    __syncthreads();   // drains vmcnt -> tile resident in LDS

    for (int h = 0; h < 2; ++h) {
        const int q = h * 4 + quad;          // logical K-seg (8 ch each)
#pragma unroll
        for (int tap = 0; tap < 9; ++tap) {
            const int kh = tap / 3, kw = tap - kh * 3;
            short8 af[2], bf[2];
#pragma unroll
            for (int i = 0; i < 2; ++i) {    // A = pixels (32 total)
                int ow = i * 16 + l15;
                int p  = kh * 65 + 2 * ow + kw;
                af[i] = __builtin_bit_cast(short8,
                    *(const uint4*)(As + p * 64 +
                                    ((q ^ ((p >> 1) & 7)) << 3)));
            }
#pragma unroll
            for (int j = 0; j < 2; ++j)      // B = weights (32 oc per wave)
                bf[j] = __builtin_bit_cast(short8,
                    *(const uint4*)(wtB +
                        ((size_t)((tap * 8 + h * 4 + quad) * 128) +
                         wn + j * 16 + l15) * 8));
#pragma unroll
            for (int i = 0; i < 2; ++i)
#pragma unroll
                for (int j = 0; j < 2; ++j)
                    acc[i][j] = __builtin_amdgcn_mfma_f32_16x16x32_bf16(
                        af[i], bf[j], acc[i][j], 0, 0, 0);
        }
    }

    // epilogue: bias+ReLU -> bf16 tile in LDS -> coalesced 8B stores
    __syncthreads();
#pragma unroll
    for (int j = 0; j < 2; ++j) {
        int n = wn + j * 16 + l15;
        float bv = bias[n];
#pragma unroll
        for (int i = 0; i < 2; ++i)
#pragma unroll
            for (int r = 0; r < 4; ++r) {
                int ml = i * 16 + quad * 4 + r;       // px 0..31
                Cs[ml * 132 + n] = bf16_bits(fmaxf(acc[i][j][r] + bv, 0.f));
            }
    }
    __syncthreads();
#pragma unroll
    for (int q2 = 0; q2 < 4; ++q2) {
        int c   = tid + 256 * q2;
        int row = c >> 5;
        int off = c & 31;
        uint2 val = *(const uint2*)(Cs + row * 132 + off * 4);
        int m  = (Mt << 5) + row;
        int b  = m >> 10;
        int rr = m & 1023;
        int oh = rr >> 5;
        int ow = rr & 31;
        size_t pix = ((size_t)(b * 33 + oh + 1) * 33 + (ow + 1));
        *(uint2*)(out + pix * 128 + off * 4) = val;
    }
}

// ---------------------------------------------------------------------------
// conv3 implicit-GEMM + fused pool (round-4 proven version): full 128-ch
// A-tile staged ONCE via async global_load_lds (full 256B lines, linear
// dest, inverse-swizzled source), single barrier. Tap loop NOT unrolled.
// M-tile 64 px (4 oh x 16 ow), N = 256. LDS 304 px * 256 B = 77824 B.
// ---------------------------------------------------------------------------
__global__ __launch_bounds__(256, 2) void conv3_gemm_pool_kernel(
    const __hip_bfloat16* __restrict__ act,
    const __hip_bfloat16* __restrict__ wtB,   // [tap][16][256][8]
    const float* __restrict__ bias,
    float* __restrict__ v /* [CHI,256], pre-zeroed */) {
    const int tid  = threadIdx.x;
    const int lane = tid & 63;
    const int w    = tid >> 6;
    const int l15  = lane & 15;
    const int quad = lane >> 4;
    const int per  = gridDim.x >> 3;
    const int Mt   = (blockIdx.x & 7) * per + (blockIdx.x >> 3);
    const int bimg = Mt >> 2;
    const int oh0  = (Mt & 3) << 2;

    __shared__ __align__(16) char smem[77824];
    ushort* As   = (ushort*)smem;
    float*  sred = (float*)smem;                 // pool alias (1 KB)

    f32x4 acc[4][4];
#pragma unroll
    for (int i = 0; i < 4; ++i)
#pragma unroll
        for (int j = 0; j < 4; ++j) acc[i][j] = (f32x4){0.f, 0.f, 0.f, 0.f};

    const int wn = w << 6;                       // wave owns 64 n-cols
    const size_t abase = ((size_t)(bimg * 33 + 2 * oh0)) * 33 * 128;
    const ushort* ap = (const ushort*)act;

    // stage 297 px x 128 ch (9 rows x 33 px), 16 chunks/px, 4864 chunks total.
#pragma unroll
    for (int it = 0; it < 19; ++it) {
        int c  = (it << 8) + tid;
        int p  = c >> 4;                 // pixel
        int t  = c & 15;                 // dest chunk-in-px
        int h  = t >> 3;                 // 64-ch half
        int ss = (t & 7) ^ ((p >> 1) & 7);
        gload_lds16(ap + abase + (size_t)p * 128 + h * 64 + ss * 8,
                    As + (size_t)c * 8);
    }
    __syncthreads();   // drains vmcnt -> all of A resident in LDS

    for (int h = 0; h < 2; ++h) {
#pragma unroll 1
        for (int tap = 0; tap < 9; ++tap) {
            const int kh = tap / 3, kw = tap - kh * 3;
#pragma unroll
            for (int ks = 0; ks < 2; ++ks) {
                short8 af[4], bf[4];
                const int sl = ks * 4 + quad;        // seg within 64-ch half
#pragma unroll
                for (int i = 0; i < 4; ++i) {
                    int p = (i * 2 + kh) * 33 + l15 * 2 + kw;
                    af[i] = __builtin_bit_cast(short8,
                        *(const uint4*)(As + p * 128 + h * 64 +
                                        (((sl ^ (p >> 1)) & 7) << 3)));
                }
#pragma unroll
                for (int j = 0; j < 4; ++j)
                    bf[j] = __builtin_bit_cast(short8,
                        *(const uint4*)(wtB +
                            ((size_t)((tap * 16 + h * 8 + sl) * 256) +
                             wn + j * 16 + l15) * 8));
#pragma unroll
                for (int i = 0; i < 4; ++i)
#pragma unroll
                    for (int j = 0; j < 4; ++j)
                        acc[i][j] = __builtin_amdgcn_mfma_f32_16x16x32_bf16(
                            af[i], bf[j], acc[i][j], 0, 0, 0);
            }
        }
    }

    // fused pool: bias+ReLU, sum over the block's 64 spatial positions
    float s4[4];
#pragma unroll
    for (int j = 0; j < 4; ++j) {
        float bv = bias[wn + j * 16 + l15];
        float s = 0.f;
#pragma unroll
        for (int i = 0; i < 4; ++i)
#pragma unroll
            for (int r = 0; r < 4; ++r)
                s += fmaxf(acc[i][j][r] + bv, 0.f);
        s += __shfl_xor(s, 16, 64);   // reduce across quads (same n)
        s += __shfl_xor(s, 32, 64);
        s4[j] = s;
    }
    __syncthreads();   // all K-loop LDS reads done before sred alias write
    if (quad == 0) {
#pragma unroll
        for (int j = 0; j < 4; ++j) sred[wn + j * 16 + l15] = s4[j];
    }
    __syncthreads();
    atomicAdd(v + (size_t)bimg * 256 + tid, sred[tid] * (1.f / 256.f));
}

// ---------------------------------------------------------------------------
// Tail: one block (256 thr) per sample; K-split GEMV stages, float4 weights.
// ---------------------------------------------------------------------------
template<int N, int K, int S, bool RELU>
__device__ __forceinline__ void gemv_stage(const float* __restrict__ w,
                                           const float* __restrict__ bias,
                                           const float* in, float* outv,
                                           float4* red4, int tid) {
    constexpr int G = N / 4;
    constexpr int CHK = K / S;
    static_assert(G * S == 256 && CHK * S == K, "stage shape");
    const int g = tid % G, s = tid / G;
    const float4* wp = (const float4*)w;
    float4 a; a.x = a.y = a.z = a.w = 0.f;
    const int k0 = s * CHK;
#pragma unroll 8
    for (int i = 0; i < CHK; ++i) {
        float x = in[k0 + i];
        float4 wv = wp[(size_t)(k0 + i) * G + g];
        a.x = fmaf(x, wv.x, a.x);
        a.y = fmaf(x, wv.y, a.y);
        a.z = fmaf(x, wv.z, a.z);
        a.w = fmaf(x, wv.w, a.w);
    }
    red4[tid] = a;
    __syncthreads();
    if (tid < N) {
        int gg = tid >> 2, e = tid & 3;
        float vv = bias[tid];
#pragma unroll
        for (int ss = 0; ss < S; ++ss) {
            const float* rp = (const float*)(red4 + ss * G + gg);
            vv += rp[e];
        }
        if (RELU) vv = fmaxf(vv, 0.f);
        outv[tid] = vv;
    }
    __syncthreads();
}

__global__ __launch_bounds__(256) void tail_kernel(
    const float* __restrict__ prop, const int* __restrict__ task_ids,
    const float* __restrict__ p1_w, const float* __restrict__ p1_b,
    const float* __restrict__ p2_w, const float* __restrict__ p2_b,
    const float* __restrict__ v,
    const float* __restrict__ f1_w, const float* __restrict__ f1_b,
    const float* __restrict__ f2_w, const float* __restrict__ f2_b,
    const float* __restrict__ task_emb,
    const float* __restrict__ g_w, const float* __restrict__ g_b,
    const float* __restrict__ h1_w, const float* __restrict__ h1_b,
    const float* __restrict__ h2_w, const float* __restrict__ h2_b,
    const float* __restrict__ h3_w, const float* __restrict__ h3_b,
    float* __restrict__ out) {
    const int b   = blockIdx.x;
    const int tid = threadIdx.x;
    const int t   = task_ids[b];
    __shared__ float sa[320];
    __shared__ float sb[288];
    __shared__ float sph[64];
    __shared__ float4 red4[256];

    sa[tid] = (tid < 256) ? v[(size_t)b * 256 + tid] : 0.f;
    if (tid < 64) {
        float h = p1_b[tid];
#pragma unroll
        for (int k = 0; k < 7; ++k) h = fmaf(prop[b * 7 + k], p1_w[k * 64 + tid], h);
        sph[tid] = fmaxf(h, 0.f);
    }
    __syncthreads();
    gemv_stage<64, 64, 16, false>(p2_w, p2_b, sph, sa + 256, red4, tid);
    gemv_stage<256, 320, 4, true>(f1_w, f1_b, sa, sb, red4, tid);
    gemv_stage<256, 256, 4, true>(f2_w, f2_b, sb, sa, red4, tid);
    if (tid < 32) sa[256 + tid] = task_emb[t * 32 + tid];
    __syncthreads();
    gemv_stage<256, 288, 4, true>(g_w, g_b, sa, sb, red4, tid);
    gemv_stage<128, 256, 8, true>(h1_w + (size_t)t * 32768, h1_b + t * 128,
                                  sb, sa, red4, tid);
    gemv_stage<128, 128, 8, true>(h2_w + (size_t)t * 16384, h2_b + t * 128,
                                  sa, sb, red4, tid);
    if (tid < 128) {
        float4 wv = ((const float4*)(h3_w + (size_t)t * 512))[tid];
        float x = sb[tid];
        float r0 = x * wv.x, r1 = x * wv.y, r2 = x * wv.z, r3 = x * wv.w;
#pragma unroll
        for (int off = 1; off < 64; off <<= 1) {
            r0 += __shfl_xor(r0, off, 64);
            r1 += __shfl_xor(r1, off, 64);
            r2 += __shfl_xor(r2, off, 64);
            r3 += __shfl_xor(r3, off, 64);
        }
        if ((tid & 63) == 0) {
            float4 rv; rv.x = r0; rv.y = r1; rv.z = r2; rv.w = r3;
            red4[tid >> 6] = rv;
        }
    }
    __syncthreads();
    if (tid < 4) {
        const float* ra = (const float*)(red4 + 0);
        const float* rb = (const float*)(red4 + 1);
        out[b * 4 + tid] = ra[tid] + rb[tid] + h3_b[t * 4 + tid];
    }
}

// ---------------------------------------------------------------------------
extern "C" void kernel_launch(void* const* d_in, const int* in_sizes, int n_in,
                              void* d_out, int out_size, void* d_ws, size_t ws_size,
                              hipStream_t stream) {
    (void)in_sizes; (void)n_in; (void)out_size;
    const float* images   = (const float*)d_in[0];
    const float* prop     = (const float*)d_in[1];
    const int*   task_ids = (const int*)d_in[2];
    const float* c1_w = (const float*)d_in[3];
    const float* c1_b = (const float*)d_in[4];
    const float* c2_w = (const float*)d_in[5];
    const float* c2_b = (const float*)d_in[6];
    const float* c3_w = (const float*)d_in[7];
    const float* c3_b = (const float*)d_in[8];
    const float* p1_w = (const float*)d_in[9];
    const float* p1_b = (const float*)d_in[10];
    const float* p2_w = (const float*)d_in[11];
    const float* p2_b = (const float*)d_in[12];
    const float* f1_w = (const float*)d_in[13];
    const float* f1_b = (const float*)d_in[14];
    const float* f2_w = (const float*)d_in[15];
    const float* f2_b = (const float*)d_in[16];
    const float* temb = (const float*)d_in[17];
    const float* g_w  = (const float*)d_in[18];
    const float* g_b  = (const float*)d_in[19];
    const float* h1_w = (const float*)d_in[20];
    const float* h1_b = (const float*)d_in[21];
    const float* h2_w = (const float*)d_in[22];
    const float* h2_b = (const float*)d_in[23];
    const float* h3_w = (const float*)d_in[24];
    const float* h3_b = (const float*)d_in[25];
    float* out = (float*)d_out;

    const size_t per_img = (size_t)65 * 65 * 64 * 2 + (size_t)33 * 33 * 128 * 2;
    const size_t fixed   = (size_t)256 * 256 * 4 + 1728 * 4 +
                           (size_t)73728 * 2 + (size_t)294912 * 2 + 4096;
    int CHI = 64;
    if (ws_size >= fixed + per_img * 256) CHI = 256;
    else if (ws_size >= fixed + per_img * 128) CHI = 128;

    char* ws = (char*)d_ws;
    size_t off = 0;
    auto alloc = [&](size_t bytes) {
        void* p = ws + off;
        off += (bytes + 255) & ~(size_t)255;
        return p;
    };
    __hip_bfloat16* act1 = (__hip_bfloat16*)alloc((size_t)CHI * 65 * 65 * 64 * 2);
    __hip_bfloat16* act2 = (__hip_bfloat16*)alloc((size_t)CHI * 33 * 33 * 128 * 2);
    float*          vbuf = (float*)alloc((size_t)256 * 256 * 4);
    __hip_bfloat16* w1b  = (__hip_bfloat16*)alloc((size_t)2048 * 2);
    __hip_bfloat16* w2t  = (__hip_bfloat16*)alloc((size_t)73728 * 2);
    __hip_bfloat16* w3t  = (__hip_bfloat16*)alloc((size_t)294912 * 2);

    halo_zero_kernel<<<dim3(CHI), 256, 0, stream>>>(
        (uint4*)act1, (uint4*)act2, (float4*)vbuf);
    repack_w1_kernel<<<8, 256, 0, stream>>>(c1_w, w1b);
    repack_w_kernel<<<DIV_UP(73728, 256), 256, 0, stream>>>(c2_w, w2t, 128, 64);
    repack_w_kernel<<<DIV_UP(294912, 256), 256, 0, stream>>>(c3_w, w3t, 256, 128);

    for (int c0 = 0; c0 < 256; c0 += CHI) {
        const float* img_c = images + (size_t)c0 * 3 * 128 * 128;
        conv1_mfma_kernel<<<dim3(16, CHI), dim3(256), 0, stream>>>(
            img_c, w1b, c1_b, act1);
        conv2_gemm_kernel<<<dim3(CHI * 32), 256, 0, stream>>>(
            act1, w2t, c2_b, act2);
        conv3_gemm_pool_kernel<<<dim3(CHI * 4), 256, 0, stream>>>(
            act2, w3t, c3_b, vbuf + (size_t)c0 * 256);
    }
    tail_kernel<<<256, 256, 0, stream>>>(prop, task_ids, p1_w, p1_b, p2_w, p2_b,
                                         vbuf, f1_w, f1_b, f2_w, f2_b, temb,
                                         g_w, g_b, h1_w, h1_b, h2_w, h2_b,
                                         h3_w, h3_b, out);
}

// Round 11
// 325.057 us; speedup vs baseline: 1.0366x; 1.0366x over previous
//
#include <hip/hip_runtime.h>
#include <hip/hip_bf16.h>

#define DIV_UP(a,b) (((a)+(b)-1)/(b))

typedef __attribute__((ext_vector_type(8))) short short8;
typedef __attribute__((ext_vector_type(4))) float f32x4;

__device__ __forceinline__ ushort bf16_bits(float x) {
    return __builtin_bit_cast(ushort, __float2bfloat16(x));
}

// async global->LDS 16B DMA: LDS dest is wave-uniform base + lane*16,
// global src is per-lane (pre-swizzled source pattern, guide rule 21)
__device__ __forceinline__ void gload_lds16(const ushort* g, ushort* l) {
    __builtin_amdgcn_global_load_lds(
        (const __attribute__((address_space(1))) void*)g,
        (__attribute__((address_space(3))) void*)l, 16, 0, 0);
}

// ---------------------------------------------------------------------------
// Merged prep: halo-zero (act1/act2/vbuf) + all three weight repacks in ONE
// launch, partitioned by blockIdx range (saves 3 serial launch overheads).
// grid = CHI + 8 + 288 + 1152 blocks of 256 threads.
// ---------------------------------------------------------------------------
__global__ __launch_bounds__(256) void prep_kernel(
    uint4* __restrict__ act1, uint4* __restrict__ act2,
    float4* __restrict__ vbuf, int CHI,
    const float* __restrict__ c1_w, __hip_bfloat16* __restrict__ w1b,
    const float* __restrict__ c2_w, __hip_bfloat16* __restrict__ w2t,
    const float* __restrict__ c3_w, __hip_bfloat16* __restrict__ w3t) {
    const int tid = threadIdx.x;
    int bx = blockIdx.x;

    if (bx < CHI) {                       // ---- halo zero for image bx ----
        const int b = bx;
        const uint4 z = {0u, 0u, 0u, 0u};
        uint4* a1 = act1 + (size_t)b * 33800;     // 65*65*64 bf16
        for (int i = tid; i < 520; i += 256) a1[i] = z;
        for (int i = tid; i < 512; i += 256) {
            int r = (i >> 3) + 1;
            a1[r * 520 + (i & 7)] = z;
        }
        uint4* a2 = act2 + (size_t)b * 17424;     // 33*33*128 bf16
        for (int i = tid; i < 528; i += 256) a2[i] = z;
        for (int i = tid; i < 512; i += 256) {
            int r = (i >> 4) + 1;
            a2[r * 528 + (i & 15)] = z;
        }
        int idx = b * 256 + tid;
        float4 zf = {0.f, 0.f, 0.f, 0.f};
        if (idx < 16384) vbuf[idx] = zf;
        return;
    }
    bx -= CHI;

    if (bx < 8) {                         // ---- conv1 weights [64][32] ----
        int t = bx * 256 + tid;           // t < 2048
        int k  = t & 31;
        int oc = t >> 5;
        w1b[t] = (k < 27) ? __float2bfloat16(c1_w[oc * 27 + k])
                          : __float2bfloat16(0.f);
        return;
    }
    bx -= 8;

    const float* src;
    __hip_bfloat16* dst;
    int O, C, t;
    if (bx < 288) {                       // ---- conv2 weights repack ----
        src = c2_w; dst = w2t; O = 128; C = 64;
        t = bx * 256 + tid;               // t < 73728
    } else {                              // ---- conv3 weights repack ----
        src = c3_w; dst = w3t; O = 256; C = 128;
        t = (bx - 288) * 256 + tid;       // t < 294912
    }
    int e   = t & 7;
    int r   = t >> 3;
    int n   = r % O;
    int q   = r / O;
    int SEG = C >> 3;
    int sg  = q % SEG;
    int tap = q / SEG;
    dst[t] = __float2bfloat16(src[(n * C + sg * 8 + e) * 9 + tap]);
}

// ---------------------------------------------------------------------------
// conv1 as MFMA implicit-GEMM (round-4 proven version):
// async-DMA input stage -> reg im2col -> swizzled Al -> MFMA -> direct stores
// ---------------------------------------------------------------------------
__global__ __launch_bounds__(256) void conv1_mfma_kernel(
    const float* __restrict__ in,
    const __hip_bfloat16* __restrict__ wB,   // [64][32] bf16
    const float* __restrict__ bias,
    __hip_bfloat16* __restrict__ out) {
    const int tid  = threadIdx.x;
    const int lane = tid & 63;
    const int wv   = tid >> 6;
    const int l15  = lane & 15;
    const int quad = lane >> 4;
    const int tile = blockIdx.x;             // 0..15, 4 oh rows each
    const int b    = blockIdx.y;
    const int oh0  = tile << 2;

    __shared__ __align__(16) char smem[30208];
    float*  sx = (float*)smem;               // [27][128] fp32, row q = c*9+r
    ushort* Al = (ushort*)(smem + 13824);    // [256][32] bf16 swizzled, 16 KB

    const float* ip  = in + (size_t)b * 3 * 128 * 128;
    const int    ih0 = 2 * oh0 - 1;

    // stage 27 rows x 128 fp32 = 864 16B chunks, linear LDS dest
#pragma unroll
    for (int it = 0; it < 4; ++it) {
        int e = (it << 8) + tid;
        if (e < 864) {
            int q = e >> 5, k = e & 31;      // row q, chunk k
            int c = q / 9, r = q - c * 9;
            int row = ih0 + r;
            if (row < 0) row = 0;            // clamp; masked in im2col
            gload_lds16((const ushort*)(ip + c * 16384 + row * 128 + k * 4),
                        (ushort*)smem + (size_t)e * 8);
        }
    }
    __syncthreads();   // drains vmcnt -> input resident in LDS

    // reg im2col: thread owns px = tid; 27 taps from sx with edge masks
    const int px = tid, ohl = px >> 6, ow = px & 63;
    union { uint4 u4[4]; ushort us[32]; } rowv;
#pragma unroll
    for (int c = 0; c < 3; ++c)
#pragma unroll
        for (int kh = 0; kh < 3; ++kh) {
            const bool rok = (ih0 + 2 * ohl + kh) >= 0;
            const float* srow = sx + (c * 9 + 2 * ohl + kh) * 128;
#pragma unroll
            for (int kw = 0; kw < 3; ++kw) {
                int iw = 2 * ow + kw - 1;
                bool ok = rok && (iw >= 0);
                float x = srow[iw < 0 ? 0 : iw];
                rowv.us[c * 9 + kh * 3 + kw] = bf16_bits(ok ? x : 0.f);
            }
        }
#pragma unroll
    for (int k = 27; k < 32; ++k) rowv.us[k] = 0;
#pragma unroll
    for (int q = 0; q < 4; ++q)
        *(uint4*)(Al + px * 32 + (((q ^ (px >> 1)) & 3) << 3)) = rowv.u4[q];

    // weight fragment (4 KB table, L2-hot): af rows = oc
    short8 af[4], bf[4];
#pragma unroll
    for (int i = 0; i < 4; ++i)
        af[i] = __builtin_bit_cast(short8,
            *(const uint4*)(wB + ((i * 16 + l15) * 32 + quad * 8)));

    __syncthreads();   // Al visible (exchange itself is intra-wave)

#pragma unroll
    for (int j = 0; j < 4; ++j) {
        int p = wv * 64 + j * 16 + l15;
        bf[j] = __builtin_bit_cast(short8,
            *(const uint4*)(Al + p * 32 + (((quad ^ (p >> 1)) & 3) << 3)));
    }
    f32x4 acc[4][4];
#pragma unroll
    for (int i = 0; i < 4; ++i)
#pragma unroll
        for (int j = 0; j < 4; ++j)
            acc[i][j] = __builtin_amdgcn_mfma_f32_16x16x32_bf16(
                af[i], bf[j], (f32x4){0.f, 0.f, 0.f, 0.f}, 0, 0, 0);

    float4 bv[4];
#pragma unroll
    for (int i = 0; i < 4; ++i)
        bv[i] = *(const float4*)(bias + i * 16 + quad * 4);

    // direct stores: D frag (col=px=j*16+l15 wave-local, row=oc=i*16+quad*4+r)
    __hip_bfloat16* ob = out + (((size_t)b * 65 + oh0 + 1) * 65 + 1) * 64;
#pragma unroll
    for (int j = 0; j < 4; ++j) {
        const int oww = j * 16 + l15;
        __hip_bfloat16* op = ob + ((size_t)(wv * 65) + oww) * 64 + quad * 4;
#pragma unroll
        for (int i = 0; i < 4; ++i) {
            union { uint2 u2; ushort us[4]; } pk;
#pragma unroll
            for (int r = 0; r < 4; ++r)
                pk.us[r] = bf16_bits(
                    fmaxf(acc[i][j][r] + ((const float*)&bv[i])[r], 0.f));
            *(uint2*)(op + i * 16) = pk.u2;
        }
    }
}

// ---------------------------------------------------------------------------
// conv2 implicit-GEMM, small-tile/high-occupancy v2 (round-8/9 proven BEST):
// M-tile = 64 px (2 oh x 32 ow), N = 128 oc; wave = 32 px x 64 oc.
// Full-3-bit XOR chunk swizzle -> af reads 2-way bank aliasing (free).
// LDS 5x65 px x 128B = 41600 B -> 3 blocks/CU (measured optimum:
// 2blk=83us, 3blk=66us, 6blk=74us).
// ---------------------------------------------------------------------------
__global__ __launch_bounds__(256, 3) void conv2_gemm_kernel(
    const __hip_bfloat16* __restrict__ act,
    const __hip_bfloat16* __restrict__ wtB,   // [tap][8][128][8]
    const float* __restrict__ bias,
    __hip_bfloat16* __restrict__ out) {
    const int tid  = threadIdx.x;
    const int lane = tid & 63;
    const int w    = tid >> 6;
    const int l15  = lane & 15;
    const int quad = lane >> 4;
    const int per  = gridDim.x >> 3;
    const int Mt   = (blockIdx.x & 7) * per + (blockIdx.x >> 3);
    const int bimg = Mt >> 4;
    const int oh0  = (Mt & 15) << 1;         // 2 output rows per tile

    __shared__ __align__(16) char smem[41600];   // 325 px * 128 B
    ushort* As = (ushort*)smem;
    ushort* Cs = (ushort*)smem;                  // epilogue alias (16.9 KB)

    f32x4 acc[2][4];
#pragma unroll
    for (int i = 0; i < 2; ++i)
#pragma unroll
        for (int j = 0; j < 4; ++j) acc[i][j] = (f32x4){0.f, 0.f, 0.f, 0.f};

    const int pxw = (w >> 1) << 5;           // wave owns 32 px
    const int wn  = (w & 1) << 6;            // wave owns 64 oc
    const size_t abase = ((size_t)(bimg * 65 + 2 * oh0)) * 65 * 64;
    const ushort* ap = (const ushort*)act;

    // stage 5 rows x 65 px x 64 ch = 2600 16B chunks, full lines.
    // dest chunk t of pixel p holds source chunk t^((p>>1)&7) (ch = 8*q)
#pragma unroll
    for (int it = 0; it < 11; ++it) {
        int c = (it << 8) + tid;
        if (c < 2600) {
            int p = c >> 3, t = c & 7;       // p = r*65 + px
            int q = t ^ ((p >> 1) & 7);
            gload_lds16(ap + abase + (size_t)p * 64 + q * 8,
                        As + (size_t)c * 8);
        }
    }
    __syncthreads();   // drains vmcnt -> tile resident in LDS

    for (int h = 0; h < 2; ++h) {
        const int q = h * 4 + quad;          // logical K-seg (8 ch each)
#pragma unroll
        for (int tap = 0; tap < 9; ++tap) {
            const int kh = tap / 3, kw = tap - kh * 3;
            short8 af[2], bf[4];
#pragma unroll
            for (int i = 0; i < 2; ++i) {    // A = pixels (32 per wave)
                int ml = pxw + i * 16 + l15;
                int p  = ((ml >> 5) * 2 + kh) * 65 + ((ml & 31) * 2 + kw);
                af[i] = __builtin_bit_cast(short8,
                    *(const uint4*)(As + p * 64 +
                                    ((q ^ ((p >> 1) & 7)) << 3)));
            }
#pragma unroll
            for (int j = 0; j < 4; ++j)      // B = weights (64 oc per wave)
                bf[j] = __builtin_bit_cast(short8,
                    *(const uint4*)(wtB +
                        ((size_t)((tap * 8 + h * 4 + quad) * 128) +
                         wn + j * 16 + l15) * 8));
#pragma unroll
            for (int i = 0; i < 2; ++i)
#pragma unroll
                for (int j = 0; j < 4; ++j)
                    acc[i][j] = __builtin_amdgcn_mfma_f32_16x16x32_bf16(
                        af[i], bf[j], acc[i][j], 0, 0, 0);
        }
    }

    // epilogue: bias+ReLU -> bf16 tile in LDS -> coalesced 8B stores
    __syncthreads();
#pragma unroll
    for (int j = 0; j < 4; ++j) {
        int n = wn + j * 16 + l15;
        float bv = bias[n];
#pragma unroll
        for (int i = 0; i < 2; ++i)
#pragma unroll
            for (int r = 0; r < 4; ++r) {
                int ml = pxw + i * 16 + quad * 4 + r;   // px 0..63
                Cs[ml * 132 + n] = bf16_bits(fmaxf(acc[i][j][r] + bv, 0.f));
            }
    }
    __syncthreads();
#pragma unroll
    for (int q2 = 0; q2 < 8; ++q2) {
        int c   = tid + 256 * q2;
        int row = c >> 5;
        int off = c & 31;
        uint2 val = *(const uint2*)(Cs + row * 132 + off * 4);
        int m  = (Mt << 6) + row;
        int b  = m >> 10;
        int rr = m & 1023;
        int oh = rr >> 5;
        int ow = rr & 31;
        size_t pix = ((size_t)(b * 33 + oh + 1) * 33 + (ow + 1));
        *(uint2*)(out + pix * 128 + off * 4) = val;
    }
}

// ---------------------------------------------------------------------------
// conv3 implicit-GEMM + fused pool (round-4 proven version): full 128-ch
// A-tile staged ONCE via async global_load_lds (full 256B lines, linear
// dest, inverse-swizzled source), single barrier. Tap loop NOT unrolled.
// M-tile 64 px (4 oh x 16 ow), N = 256. LDS 304 px * 256 B = 77824 B.
// ---------------------------------------------------------------------------
__global__ __launch_bounds__(256, 2) void conv3_gemm_pool_kernel(
    const __hip_bfloat16* __restrict__ act,
    const __hip_bfloat16* __restrict__ wtB,   // [tap][16][256][8]
    const float* __restrict__ bias,
    float* __restrict__ v /* [CHI,256], pre-zeroed */) {
    const int tid  = threadIdx.x;
    const int lane = tid & 63;
    const int w    = tid >> 6;
    const int l15  = lane & 15;
    const int quad = lane >> 4;
    const int per  = gridDim.x >> 3;
    const int Mt   = (blockIdx.x & 7) * per + (blockIdx.x >> 3);
    const int bimg = Mt >> 2;
    const int oh0  = (Mt & 3) << 2;

    __shared__ __align__(16) char smem[77824];
    ushort* As   = (ushort*)smem;
    float*  sred = (float*)smem;                 // pool alias (1 KB)

    f32x4 acc[4][4];
#pragma unroll
    for (int i = 0; i < 4; ++i)
#pragma unroll
        for (int j = 0; j < 4; ++j) acc[i][j] = (f32x4){0.f, 0.f, 0.f, 0.f};

    const int wn = w << 6;                       // wave owns 64 n-cols
    const size_t abase = ((size_t)(bimg * 33 + 2 * oh0)) * 33 * 128;
    const ushort* ap = (const ushort*)act;

    // stage 297 px x 128 ch (9 rows x 33 px), 16 chunks/px, 4864 chunks total.
#pragma unroll
    for (int it = 0; it < 19; ++it) {
        int c  = (it << 8) + tid;
        int p  = c >> 4;                 // pixel
        int t  = c & 15;                 // dest chunk-in-px
        int h  = t >> 3;                 // 64-ch half
        int ss = (t & 7) ^ ((p >> 1) & 7);
        gload_lds16(ap + abase + (size_t)p * 128 + h * 64 + ss * 8,
                    As + (size_t)c * 8);
    }
    __syncthreads();   // drains vmcnt -> all of A resident in LDS

    for (int h = 0; h < 2; ++h) {
#pragma unroll 1
        for (int tap = 0; tap < 9; ++tap) {
            const int kh = tap / 3, kw = tap - kh * 3;
#pragma unroll
            for (int ks = 0; ks < 2; ++ks) {
                short8 af[4], bf[4];
                const int sl = ks * 4 + quad;        // seg within 64-ch half
#pragma unroll
                for (int i = 0; i < 4; ++i) {
                    int p = (i * 2 + kh) * 33 + l15 * 2 + kw;
                    af[i] = __builtin_bit_cast(short8,
                        *(const uint4*)(As + p * 128 + h * 64 +
                                        (((sl ^ (p >> 1)) & 7) << 3)));
                }
#pragma unroll
                for (int j = 0; j < 4; ++j)
                    bf[j] = __builtin_bit_cast(short8,
                        *(const uint4*)(wtB +
                            ((size_t)((tap * 16 + h * 8 + sl) * 256) +
                             wn + j * 16 + l15) * 8));
#pragma unroll
                for (int i = 0; i < 4; ++i)
#pragma unroll
                    for (int j = 0; j < 4; ++j)
                        acc[i][j] = __builtin_amdgcn_mfma_f32_16x16x32_bf16(
                            af[i], bf[j], acc[i][j], 0, 0, 0);
            }
        }
    }

    // fused pool: bias+ReLU, sum over the block's 64 spatial positions
    float s4[4];
#pragma unroll
    for (int j = 0; j < 4; ++j) {
        float bv = bias[wn + j * 16 + l15];
        float s = 0.f;
#pragma unroll
        for (int i = 0; i < 4; ++i)
#pragma unroll
            for (int r = 0; r < 4; ++r)
                s += fmaxf(acc[i][j][r] + bv, 0.f);
        s += __shfl_xor(s, 16, 64);   // reduce across quads (same n)
        s += __shfl_xor(s, 32, 64);
        s4[j] = s;
    }
    __syncthreads();   // all K-loop LDS reads done before sred alias write
    if (quad == 0) {
#pragma unroll
        for (int j = 0; j < 4; ++j) sred[wn + j * 16 + l15] = s4[j];
    }
    __syncthreads();
    atomicAdd(v + (size_t)bimg * 256 + tid, sred[tid] * (1.f / 256.f));
}

// ---------------------------------------------------------------------------
// Tail: one block (256 thr) per sample; K-split GEMV stages, float4 weights.
// ---------------------------------------------------------------------------
template<int N, int K, int S, bool RELU>
__device__ __forceinline__ void gemv_stage(const float* __restrict__ w,
                                           const float* __restrict__ bias,
                                           const float* in, float* outv,
                                           float4* red4, int tid) {
    constexpr int G = N / 4;
    constexpr int CHK = K / S;
    static_assert(G * S == 256 && CHK * S == K, "stage shape");
    const int g = tid % G, s = tid / G;
    const float4* wp = (const float4*)w;
    float4 a; a.x = a.y = a.z = a.w = 0.f;
    const int k0 = s * CHK;
#pragma unroll 8
    for (int i = 0; i < CHK; ++i) {
        float x = in[k0 + i];
        float4 wv = wp[(size_t)(k0 + i) * G + g];
        a.x = fmaf(x, wv.x, a.x);
        a.y = fmaf(x, wv.y, a.y);
        a.z = fmaf(x, wv.z, a.z);
        a.w = fmaf(x, wv.w, a.w);
    }
    red4[tid] = a;
    __syncthreads();
    if (tid < N) {
        int gg = tid >> 2, e = tid & 3;
        float vv = bias[tid];
#pragma unroll
        for (int ss = 0; ss < S; ++ss) {
            const float* rp = (const float*)(red4 + ss * G + gg);
            vv += rp[e];
        }
        if (RELU) vv = fmaxf(vv, 0.f);
        outv[tid] = vv;
    }
    __syncthreads();
}

__global__ __launch_bounds__(256) void tail_kernel(
    const float* __restrict__ prop, const int* __restrict__ task_ids,
    const float* __restrict__ p1_w, const float* __restrict__ p1_b,
    const float* __restrict__ p2_w, const float* __restrict__ p2_b,
    const float* __restrict__ v,
    const float* __restrict__ f1_w, const float* __restrict__ f1_b,
    const float* __restrict__ f2_w, const float* __restrict__ f2_b,
    const float* __restrict__ task_emb,
    const float* __restrict__ g_w, const float* __restrict__ g_b,
    const float* __restrict__ h1_w, const float* __restrict__ h1_b,
    const float* __restrict__ h2_w, const float* __restrict__ h2_b,
    const float* __restrict__ h3_w, const float* __restrict__ h3_b,
    float* __restrict__ out) {
    const int b   = blockIdx.x;
    const int tid = threadIdx.x;
    const int t   = task_ids[b];
    __shared__ float sa[320];
    __shared__ float sb[288];
    __shared__ float sph[64];
    __shared__ float4 red4[256];

    sa[tid] = (tid < 256) ? v[(size_t)b * 256 + tid] : 0.f;
    if (tid < 64) {
        float h = p1_b[tid];
#pragma unroll
        for (int k = 0; k < 7; ++k) h = fmaf(prop[b * 7 + k], p1_w[k * 64 + tid], h);
        sph[tid] = fmaxf(h, 0.f);
    }
    __syncthreads();
    gemv_stage<64, 64, 16, false>(p2_w, p2_b, sph, sa + 256, red4, tid);
    gemv_stage<256, 320, 4, true>(f1_w, f1_b, sa, sb, red4, tid);
    gemv_stage<256, 256, 4, true>(f2_w, f2_b, sb, sa, red4, tid);
    if (tid < 32) sa[256 + tid] = task_emb[t * 32 + tid];
    __syncthreads();
    gemv_stage<256, 288, 4, true>(g_w, g_b, sa, sb, red4, tid);
    gemv_stage<128, 256, 8, true>(h1_w + (size_t)t * 32768, h1_b + t * 128,
                                  sb, sa, red4, tid);
    gemv_stage<128, 128, 8, true>(h2_w + (size_t)t * 16384, h2_b + t * 128,
                                  sa, sb, red4, tid);
    if (tid < 128) {
        float4 wv = ((const float4*)(h3_w + (size_t)t * 512))[tid];
        float x = sb[tid];
        float r0 = x * wv.x, r1 = x * wv.y, r2 = x * wv.z, r3 = x * wv.w;
#pragma unroll
        for (int off = 1; off < 64; off <<= 1) {
            r0 += __shfl_xor(r0, off, 64);
            r1 += __shfl_xor(r1, off, 64);
            r2 += __shfl_xor(r2, off, 64);
            r3 += __shfl_xor(r3, off, 64);
        }
        if ((tid & 63) == 0) {
            float4 rv; rv.x = r0; rv.y = r1; rv.z = r2; rv.w = r3;
            red4[tid >> 6] = rv;
        }
    }
    __syncthreads();
    if (tid < 4) {
        const float* ra = (const float*)(red4 + 0);
        const float* rb = (const float*)(red4 + 1);
        out[b * 4 + tid] = ra[tid] + rb[tid] + h3_b[t * 4 + tid];
    }
}

// ---------------------------------------------------------------------------
extern "C" void kernel_launch(void* const* d_in, const int* in_sizes, int n_in,
                              void* d_out, int out_size, void* d_ws, size_t ws_size,
                              hipStream_t stream) {
    (void)in_sizes; (void)n_in; (void)out_size;
    const float* images   = (const float*)d_in[0];
    const float* prop     = (const float*)d_in[1];
    const int*   task_ids = (const int*)d_in[2];
    const float* c1_w = (const float*)d_in[3];
    const float* c1_b = (const float*)d_in[4];
    const float* c2_w = (const float*)d_in[5];
    const float* c2_b = (const float*)d_in[6];
    const float* c3_w = (const float*)d_in[7];
    const float* c3_b = (const float*)d_in[8];
    const float* p1_w = (const float*)d_in[9];
    const float* p1_b = (const float*)d_in[10];
    const float* p2_w = (const float*)d_in[11];
    const float* p2_b = (const float*)d_in[12];
    const float* f1_w = (const float*)d_in[13];
    const float* f1_b = (const float*)d_in[14];
    const float* f2_w = (const float*)d_in[15];
    const float* f2_b = (const float*)d_in[16];
    const float* temb = (const float*)d_in[17];
    const float* g_w  = (const float*)d_in[18];
    const float* g_b  = (const float*)d_in[19];
    const float* h1_w = (const float*)d_in[20];
    const float* h1_b = (const float*)d_in[21];
    const float* h2_w = (const float*)d_in[22];
    const float* h2_b = (const float*)d_in[23];
    const float* h3_w = (const float*)d_in[24];
    const float* h3_b = (const float*)d_in[25];
    float* out = (float*)d_out;

    const size_t per_img = (size_t)65 * 65 * 64 * 2 + (size_t)33 * 33 * 128 * 2;
    const size_t fixed   = (size_t)256 * 256 * 4 + 1728 * 4 +
                           (size_t)73728 * 2 + (size_t)294912 * 2 + 4096;
    int CHI = 64;
    if (ws_size >= fixed + per_img * 256) CHI = 256;
    else if (ws_size >= fixed + per_img * 128) CHI = 128;

    char* ws = (char*)d_ws;
    size_t off = 0;
    auto alloc = [&](size_t bytes) {
        void* p = ws + off;
        off += (bytes + 255) & ~(size_t)255;
        return p;
    };
    __hip_bfloat16* act1 = (__hip_bfloat16*)alloc((size_t)CHI * 65 * 65 * 64 * 2);
    __hip_bfloat16* act2 = (__hip_bfloat16*)alloc((size_t)CHI * 33 * 33 * 128 * 2);
    float*          vbuf = (float*)alloc((size_t)256 * 256 * 4);
    __hip_bfloat16* w1b  = (__hip_bfloat16*)alloc((size_t)2048 * 2);
    __hip_bfloat16* w2t  = (__hip_bfloat16*)alloc((size_t)73728 * 2);
    __hip_bfloat16* w3t  = (__hip_bfloat16*)alloc((size_t)294912 * 2);

    prep_kernel<<<dim3(CHI + 8 + 288 + 1152), 256, 0, stream>>>(
        (uint4*)act1, (uint4*)act2, (float4*)vbuf, CHI,
        c1_w, w1b, c2_w, w2t, c3_w, w3t);

    for (int c0 = 0; c0 < 256; c0 += CHI) {
        const float* img_c = images + (size_t)c0 * 3 * 128 * 128;
        conv1_mfma_kernel<<<dim3(16, CHI), dim3(256), 0, stream>>>(
            img_c, w1b, c1_b, act1);
        conv2_gemm_kernel<<<dim3(CHI * 16), 256, 0, stream>>>(
            act1, w2t, c2_b, act2);
        conv3_gemm_pool_kernel<<<dim3(CHI * 4), 256, 0, stream>>>(
            act2, w3t, c3_b, vbuf + (size_t)c0 * 256);
    }
    tail_kernel<<<256, 256, 0, stream>>>(prop, task_ids, p1_w, p1_b, p2_w, p2_b,
                                         vbuf, f1_w, f1_b, f2_w, f2_b, temb,
                                         g_w, g_b, h1_w, h1_b, h2_w, h2_b,
                                         h3_w, h3_b, out);
}